// Round 1
// baseline (695.449 us; speedup 1.0000x reference)
//
#include <hip/hip_runtime.h>

#define DEV __device__ __forceinline__

typedef __attribute__((ext_vector_type(8))) short short8_t;
typedef __attribute__((ext_vector_type(4))) float float4_t;
typedef __attribute__((ext_vector_type(4))) unsigned short ushort4_t;
typedef __attribute__((ext_vector_type(8))) unsigned short ushort8_t;

#define ATT_SCALE 0.10206207261596577f  // 96^-0.5

DEV unsigned short f2bf(float f) {
  unsigned u = __float_as_uint(f);
  u += 0x7fffu + ((u >> 16) & 1u);
  return (unsigned short)(u >> 16);
}
DEV float bf2f(unsigned short h) { return __uint_as_float(((unsigned)h) << 16); }

DEV float4_t mfma16(short8_t a, short8_t b, float4_t c) {
  return __builtin_amdgcn_mfma_f32_16x16x32_bf16(a, b, c, 0, 0, 0);
}

DEV void gl_lds16(const void* g, void* l) {
  __builtin_amdgcn_global_load_lds((__attribute__((address_space(1))) void*)g,
                                   (__attribute__((address_space(3))) void*)l, 16, 0, 0);
}

// ---------------------------------------------------------------- weight cvt
__global__ __launch_bounds__(256) void cvt_kernel(const float* __restrict__ s,
                                                  unsigned short* __restrict__ d, int n4) {
  int i = blockIdx.x * 256 + threadIdx.x;
  if (i < n4) {
    float4_t v = ((const float4_t*)s)[i];
    ushort4_t o = {f2bf(v[0]), f2bf(v[1]), f2bf(v[2]), f2bf(v[3])};
    ((ushort4_t*)d)[i] = o;
  }
}

// ---------------------------------------------------------------- depthwise conv
__global__ __launch_bounds__(256) void dwconv_kernel(const float* __restrict__ img,
    const float* __restrict__ wgt, const float* __restrict__ wb, float* __restrict__ h3) {
  __shared__ float wsm[256];
  const int bc = blockIdx.x;  // b*3+c
  const int c = bc % 3;
  const int tid = threadIdx.x;
  wsm[tid] = wgt[c * 256 + tid];
  __syncthreads();
  if (tid < 196) {
    const int ph = tid / 14, pwv = tid % 14;
    const float* ip = img + (size_t)bc * (222 * 222);
    float acc = 0.f;
#pragma unroll
    for (int i = 0; i < 16; ++i) {
      const int r = ph * 16 - 1 + i;
      if ((unsigned)r < 222u) {
        const float* rp = ip + r * 222;
#pragma unroll
        for (int j = 0; j < 16; ++j) {
          const int cc = pwv * 16 - 1 + j;
          if ((unsigned)cc < 222u) acc += rp[cc] * wsm[i * 16 + j];
        }
      }
    }
    h3[(size_t)bc * 196 + tid] = acc + wb[c];
  }
}

// ---------------------------------------------------------------- LN1 (+pos, +gate stats)
__global__ __launch_bounds__(256) void ln1_kernel(const float* __restrict__ x,
    const float* __restrict__ pos, const float* __restrict__ sG, const float* __restrict__ bG,
    unsigned short* __restrict__ xln, float* __restrict__ maxn, float* __restrict__ aven) {
  __shared__ float rA[4], rB[4], rC[4], rD[4];
  const int row = blockIdx.x, tid = threadIdx.x;
  const int n = row % 196;
  const float* xr = x + (size_t)row * 768;
  const float* pr = pos + (size_t)n * 768;
  float v0 = xr[tid] + pr[tid];
  float v1 = xr[tid + 256] + pr[tid + 256];
  float v2 = xr[tid + 512] + pr[tid + 512];
  float sm = v0 + v1 + v2;
  float sq = v0 * v0 + v1 * v1 + v2 * v2;
  for (int o = 32; o; o >>= 1) { sm += __shfl_xor(sm, o); sq += __shfl_xor(sq, o); }
  if ((tid & 63) == 0) { rA[tid >> 6] = sm; rB[tid >> 6] = sq; }
  __syncthreads();
  const float mean = (rA[0] + rA[1] + rA[2] + rA[3]) * (1.f / 768.f);
  const float var = (rB[0] + rB[1] + rB[2] + rB[3]) * (1.f / 768.f) - mean * mean;
  const float rstd = rsqrtf(var + 1e-5f);
  float y0 = (v0 - mean) * rstd * sG[tid] + bG[tid];
  float y1 = (v1 - mean) * rstd * sG[tid + 256] + bG[tid + 256];
  float y2 = (v2 - mean) * rstd * sG[tid + 512] + bG[tid + 512];
  unsigned short* xo = xln + (size_t)row * 768;
  xo[tid] = f2bf(y0); xo[tid + 256] = f2bf(y1); xo[tid + 512] = f2bf(y2);
  float mx = fmaxf(y0, fmaxf(y1, y2));
  float sy = y0 + y1 + y2;
  for (int o = 32; o; o >>= 1) { mx = fmaxf(mx, __shfl_xor(mx, o)); sy += __shfl_xor(sy, o); }
  if ((tid & 63) == 0) { rC[tid >> 6] = mx; rD[tid >> 6] = sy; }
  __syncthreads();
  if (tid == 0) {
    maxn[row] = fmaxf(fmaxf(rC[0], rC[1]), fmaxf(rC[2], rC[3]));
    aven[row] = (rD[0] + rD[1] + rD[2] + rD[3]) * (1.f / 768.f);
  }
}

// ---------------------------------------------------------------- LN2
__global__ __launch_bounds__(256) void ln2_kernel(const float* __restrict__ x2,
    const float* __restrict__ sG, const float* __restrict__ bG, unsigned short* __restrict__ h2) {
  __shared__ float rA[4], rB[4];
  const int row = blockIdx.x, tid = threadIdx.x;
  const float* xr = x2 + (size_t)row * 768;
  float v0 = xr[tid], v1 = xr[tid + 256], v2 = xr[tid + 512];
  float sm = v0 + v1 + v2;
  float sq = v0 * v0 + v1 * v1 + v2 * v2;
  for (int o = 32; o; o >>= 1) { sm += __shfl_xor(sm, o); sq += __shfl_xor(sq, o); }
  if ((tid & 63) == 0) { rA[tid >> 6] = sm; rB[tid >> 6] = sq; }
  __syncthreads();
  const float mean = (rA[0] + rA[1] + rA[2] + rA[3]) * (1.f / 768.f);
  const float var = (rB[0] + rB[1] + rB[2] + rB[3]) * (1.f / 768.f) - mean * mean;
  const float rstd = rsqrtf(var + 1e-5f);
  unsigned short* xo = h2 + (size_t)row * 768;
  xo[tid]       = f2bf((v0 - mean) * rstd * sG[tid] + bG[tid]);
  xo[tid + 256] = f2bf((v1 - mean) * rstd * sG[tid + 256] + bG[tid + 256]);
  xo[tid + 512] = f2bf((v2 - mean) * rstd * sG[tid + 512] + bG[tid + 512]);
}

// ---------------------------------------------------------------- gate
__global__ __launch_bounds__(256) void gate1_kernel(const float* __restrict__ maxn,
    const float* __restrict__ aven, float* __restrict__ aveg, float* __restrict__ s1) {
  __shared__ float rA[4], rB[4], rC[4], rD[4];
  const int b = blockIdx.x, tid = threadIdx.x;
  const bool ok = tid < 196;
  const float mv = ok ? maxn[b * 196 + tid] : -1e30f;
  const float av = ok ? aven[b * 196 + tid] : 0.f;
  float m = mv, sa = av;
  for (int o = 32; o; o >>= 1) { m = fmaxf(m, __shfl_xor(m, o)); sa += __shfl_xor(sa, o); }
  if ((tid & 63) == 0) { rA[tid >> 6] = m; rB[tid >> 6] = sa; }
  __syncthreads();
  const float maxg = fmaxf(fmaxf(rA[0], rA[1]), fmaxf(rA[2], rA[3]));
  const float avg = (rB[0] + rB[1] + rB[2] + rB[3]) * (1.f / 196.f);
  if (tid == 0) aveg[b] = avg;
  const float t1 = ok ? maxg * mv : -1e30f;
  float m2 = t1;
  for (int o = 32; o; o >>= 1) m2 = fmaxf(m2, __shfl_xor(m2, o));
  if ((tid & 63) == 0) rC[tid >> 6] = m2;
  __syncthreads();
  const float m2g = fmaxf(fmaxf(rC[0], rC[1]), fmaxf(rC[2], rC[3]));
  const float e = ok ? __expf(t1 - m2g) : 0.f;
  float se = e;
  for (int o = 32; o; o >>= 1) se += __shfl_xor(se, o);
  if ((tid & 63) == 0) rD[tid >> 6] = se;
  __syncthreads();
  const float seg = rD[0] + rD[1] + rD[2] + rD[3];
  if (ok) s1[b * 196 + tid] = e / seg;
}

__global__ __launch_bounds__(64) void gate2_kernel(const float* __restrict__ aveg,
    const float* __restrict__ aven, const float* __restrict__ s1, float* __restrict__ gate) {
  const int n = blockIdx.x, bb = threadIdx.x;  // bb = batch index, 64 lanes
  const float t2 = aveg[bb] * aven[bb * 196 + n];
  float m = t2;
  for (int o = 32; o; o >>= 1) m = fmaxf(m, __shfl_xor(m, o));
  const float e = __expf(t2 - m);
  float ssum = e;
  for (int o = 32; o; o >>= 1) ssum += __shfl_xor(ssum, o);
  gate[bb * 196 + n] = s1[bb * 196 + n] * e / ssum;
}

// ---------------------------------------------------------------- GEMM (A @ W^T), m97 structure
enum { M_QKV = 0, M_PROJ = 1, M_GELU = 2, M_FC2 = 3 };

template <int MODE>
__global__ __launch_bounds__(256, 2) void gemm_bt(
    const unsigned short* __restrict__ A, const unsigned short* __restrict__ W,
    int K, int Nd,
    const float* __restrict__ bias,
    const float* __restrict__ res0, const float* __restrict__ res1,
    const float* __restrict__ gate, const float* __restrict__ h3,
    const float* __restrict__ pw, const float* __restrict__ pwb,
    unsigned short* __restrict__ oQ, unsigned short* __restrict__ oK,
    unsigned short* __restrict__ oV, unsigned short* __restrict__ oVT,
    float* __restrict__ oF, unsigned short* __restrict__ oB) {
  __shared__ __align__(16) unsigned short smem[8192];  // A tile [0,4096) shorts, B tile [4096,8192)
  const int tid = threadIdx.x;
  const int w = tid >> 6, lane = tid & 63;
  const int l15 = lane & 15, quad = lane >> 4;
  const int m0 = blockIdx.x * 128, n0 = blockIdx.y * 128;

  const int row0 = tid >> 2, kc0 = (tid & 3) << 3;
  const size_t arow0 = (size_t)(m0 + row0) * K + kc0;
  const size_t arow1 = (size_t)(m0 + 64 + row0) * K + kc0;
  const size_t brow0 = (size_t)(n0 + row0) * K + kc0;
  const size_t brow1 = (size_t)(n0 + 64 + row0) * K + kc0;
  char* sb = (char*)smem;
  const int ldsA0 = w * 1024, ldsA1 = 4096 + w * 1024;
  const int ldsB0 = 8192 + w * 1024, ldsB1 = 12288 + w * 1024;

  float4_t acc[4][4];
#pragma unroll
  for (int i = 0; i < 4; ++i)
#pragma unroll
    for (int j = 0; j < 4; ++j) acc[i][j] = (float4_t){0.f, 0.f, 0.f, 0.f};

  const int wm = (w >> 1) << 6, wn = (w & 1) << 6;
  const unsigned short* as_ = smem;
  const unsigned short* bs_ = smem + 4096;

  for (int kt = 0; kt < K; kt += 32) {
    gl_lds16(A + arow0 + kt, sb + ldsA0);
    gl_lds16(A + arow1 + kt, sb + ldsA1);
    gl_lds16(W + brow0 + kt, sb + ldsB0);
    gl_lds16(W + brow1 + kt, sb + ldsB1);
    __syncthreads();
    short8_t af[4], bfr[4];
#pragma unroll
    for (int mi = 0; mi < 4; ++mi)
      af[mi] = *(const short8_t*)(as_ + (wm + mi * 16 + l15) * 32 + quad * 8);
#pragma unroll
    for (int ni = 0; ni < 4; ++ni)
      bfr[ni] = *(const short8_t*)(bs_ + (wn + ni * 16 + l15) * 32 + quad * 8);
#pragma unroll
    for (int mi = 0; mi < 4; ++mi)
#pragma unroll
      for (int ni = 0; ni < 4; ++ni)
        acc[mi][ni] = mfma16(af[mi], bfr[ni], acc[mi][ni]);
    __syncthreads();
  }

  if (MODE == M_QKV) {
    const int sel = n0 / 768;  // block-uniform: 0=q 1=k 2=v
    const int db = n0 - sel * 768 + wn;
#pragma unroll
    for (int mi = 0; mi < 4; ++mi) {
#pragma unroll
      for (int r = 0; r < 4; ++r) {
        const int m = m0 + wm + mi * 16 + quad * 4 + r;
        const int b = m / 196, n = m - b * 196;
        const size_t base = (size_t)b * (8 * 224 * 96) + (size_t)n * 96;
        float gv = 0.f, h30 = 0.f, h31 = 0.f, h32 = 0.f;
        if (sel == 2) {
          gv = gate[m];
          h30 = h3[(b * 3 + 0) * 196 + n];
          h31 = h3[(b * 3 + 1) * 196 + n];
          h32 = h3[(b * 3 + 2) * 196 + n];
        }
#pragma unroll
        for (int ni = 0; ni < 4; ++ni) {
          const int dcol = db + ni * 16 + l15;
          const int hh = dcol / 96, dh = dcol - hh * 96;
          const size_t addr = base + (size_t)hh * (224 * 96) + dh;
          const float c = acc[mi][ni][r];
          if (sel == 0) oQ[addr] = f2bf(c);
          else if (sel == 1) oK[addr] = f2bf(c);
          else {
            const float v = c * gv + h30 * pw[dcol * 3] + h31 * pw[dcol * 3 + 1] +
                            h32 * pw[dcol * 3 + 2] + pwb[dcol];
            oV[addr] = f2bf(v);
            oVT[((size_t)b * 8 + hh) * (96 * 224) + (size_t)dh * 224 + n] = f2bf(v);
          }
        }
      }
    }
  } else if (MODE == M_PROJ || MODE == M_FC2) {
#pragma unroll
    for (int mi = 0; mi < 4; ++mi)
#pragma unroll
      for (int r = 0; r < 4; ++r) {
        const int m = m0 + wm + mi * 16 + quad * 4 + r;
        const int n = m % 196;
        const float* rr0 = res0 + (size_t)m * 768;
        float* oo = oF + (size_t)m * 768;
#pragma unroll
        for (int ni = 0; ni < 4; ++ni) {
          const int col = n0 + wn + ni * 16 + l15;
          float v = acc[mi][ni][r] + bias[col] + rr0[col];
          if (MODE == M_PROJ) v += res1[(size_t)n * 768 + col];
          oo[col] = v;
        }
      }
  } else {  // M_GELU
#pragma unroll
    for (int mi = 0; mi < 4; ++mi)
#pragma unroll
      for (int r = 0; r < 4; ++r) {
        const int m = m0 + wm + mi * 16 + quad * 4 + r;
        unsigned short* oo = oB + (size_t)m * Nd;
#pragma unroll
        for (int ni = 0; ni < 4; ++ni) {
          const int col = n0 + wn + ni * 16 + l15;
          const float t = acc[mi][ni][r] + bias[col];
          const float g = 0.5f * t * (1.f + erff(t * 0.70710678118654752f));
          oo[col] = f2bf(g);
        }
      }
  }
}

// ---------------------------------------------------------------- qv=q+v, vT pad zero
__global__ __launch_bounds__(256) void qkvpost_kernel(unsigned short* __restrict__ qg,
    const unsigned short* __restrict__ vg, unsigned short* __restrict__ vt) {
  const int i = blockIdx.x * 256 + threadIdx.x;  // 0..1376255
  {
    ushort8_t q = ((const ushort8_t*)qg)[i];
    ushort8_t v = ((const ushort8_t*)vg)[i];
    ushort8_t o;
#pragma unroll
    for (int j = 0; j < 8; ++j) o[j] = f2bf(bf2f(q[j]) + bf2f(v[j]));
    ((ushort8_t*)qg)[i] = o;
  }
  {
    const int bd = i / 28, cc = i - bd * 28;  // bd < 512*96
    vt[(size_t)bd * 224 + 196 + cc] = 0;
  }
}

// ---------------------------------------------------------------- fused attention
__global__ __launch_bounds__(256, 2) void attn_kernel(
    const unsigned short* __restrict__ qv, const unsigned short* __restrict__ kg,
    const unsigned short* __restrict__ vt, unsigned short* __restrict__ att) {
  __shared__ __align__(16) unsigned short p_s[4][16][240];
  const int bh = blockIdx.x, b = bh >> 3, h = bh & 7;
  const int tid = threadIdx.x, w = tid >> 6, lane = tid & 63;
  const int l15 = lane & 15, quad = lane >> 4;
  const unsigned short* qb = qv + (size_t)bh * (224 * 96);
  const unsigned short* kb = kg + (size_t)bh * (224 * 96);
  const unsigned short* vb = vt + (size_t)bh * (96 * 224);
  for (int i = lane; i < 256; i += 64) p_s[w][i >> 4][208 + (i & 15)] = 0;

  for (int qt = w; qt < 13; qt += 4) {
    const unsigned short* qr = qb + (qt * 16 + l15) * 96 + quad * 8;
    short8_t a0 = *(const short8_t*)(qr);
    short8_t a1 = *(const short8_t*)(qr + 32);
    short8_t a2 = *(const short8_t*)(qr + 64);
    float4_t S[13];
#pragma unroll
    for (int c = 0; c < 13; ++c) S[c] = (float4_t){0.f, 0.f, 0.f, 0.f};
#pragma unroll
    for (int c = 0; c < 13; ++c) {
      const unsigned short* kr = kb + (c * 16 + l15) * 96 + quad * 8;
      S[c] = mfma16(a0, *(const short8_t*)(kr), S[c]);
      S[c] = mfma16(a1, *(const short8_t*)(kr + 32), S[c]);
      S[c] = mfma16(a2, *(const short8_t*)(kr + 64), S[c]);
    }
    float mx[4] = {-1e30f, -1e30f, -1e30f, -1e30f};
#pragma unroll
    for (int c = 0; c < 13; ++c) {
      const bool okc = (c * 16 + l15) < 196;
#pragma unroll
      for (int r = 0; r < 4; ++r) {
        const float v = S[c][r] * ATT_SCALE;
        S[c][r] = okc ? v : -1e30f;
        mx[r] = fmaxf(mx[r], S[c][r]);
      }
    }
#pragma unroll
    for (int o = 1; o <= 8; o <<= 1)
#pragma unroll
      for (int r = 0; r < 4; ++r) mx[r] = fmaxf(mx[r], __shfl_xor(mx[r], o));
    float sum[4] = {0.f, 0.f, 0.f, 0.f};
#pragma unroll
    for (int c = 0; c < 13; ++c)
#pragma unroll
      for (int r = 0; r < 4; ++r) {
        const float e = __expf(S[c][r] - mx[r]);
        S[c][r] = e;
        sum[r] += e;
      }
#pragma unroll
    for (int o = 1; o <= 8; o <<= 1)
#pragma unroll
      for (int r = 0; r < 4; ++r) sum[r] += __shfl_xor(sum[r], o);
    float inv[4];
#pragma unroll
    for (int r = 0; r < 4; ++r) inv[r] = 1.f / sum[r];
#pragma unroll
    for (int c = 0; c < 13; ++c)
#pragma unroll
      for (int r = 0; r < 4; ++r)
        p_s[w][quad * 4 + r][c * 16 + l15] = f2bf(S[c][r] * inv[r]);

    float4_t O[6];
#pragma unroll
    for (int ni = 0; ni < 6; ++ni) O[ni] = (float4_t){0.f, 0.f, 0.f, 0.f};
#pragma unroll
    for (int s = 0; s < 7; ++s) {
      short8_t pa = *(const short8_t*)(&p_s[w][l15][s * 32 + quad * 8]);
#pragma unroll
      for (int ni = 0; ni < 6; ++ni)
        O[ni] = mfma16(pa, *(const short8_t*)(vb + (ni * 16 + l15) * 224 + s * 32 + quad * 8), O[ni]);
    }
    unsigned short* ab = att + (size_t)(b * 196) * 768 + h * 96;
#pragma unroll
    for (int ni = 0; ni < 6; ++ni)
#pragma unroll
      for (int r = 0; r < 4; ++r) {
        const int row = qt * 16 + quad * 4 + r;
        if (row < 196) ab[(size_t)row * 768 + ni * 16 + l15] = f2bf(O[ni][r]);
      }
  }
}

// ---------------------------------------------------------------- launch
extern "C" void kernel_launch(void* const* d_in, const int* in_sizes, int n_in,
                              void* d_out, int out_size, void* d_ws, size_t ws_size,
                              hipStream_t stream) {
  (void)in_sizes; (void)n_in; (void)out_size; (void)ws_size;
  const float* x      = (const float*)d_in[0];
  const float* xE     = (const float*)d_in[1];
  const float* pos    = (const float*)d_in[2];
  const float* dw_w   = (const float*)d_in[3];
  const float* dw_b   = (const float*)d_in[4];
  const float* pw_w   = (const float*)d_in[5];
  const float* pw_b   = (const float*)d_in[6];
  const float* qkv_w  = (const float*)d_in[7];
  const float* proj_w = (const float*)d_in[8];
  const float* proj_b = (const float*)d_in[9];
  const float* ln1_s  = (const float*)d_in[10];
  const float* ln1_b  = (const float*)d_in[11];
  const float* ln2_s  = (const float*)d_in[12];
  const float* ln2_b  = (const float*)d_in[13];
  const float* fc1_w  = (const float*)d_in[14];
  const float* fc1_b  = (const float*)d_in[15];
  const float* fc2_w  = (const float*)d_in[16];
  const float* fc2_b  = (const float*)d_in[17];
  float* out = (float*)d_out;

  char* ws = (char*)d_ws;
  size_t off = 0;
  auto alloc = [&](size_t bytes) -> void* {
    void* p = ws + off;
    off += (bytes + 255) & ~(size_t)255;
    return p;
  };
  unsigned short* wqkv  = (unsigned short*)alloc(1769472ull * 2);
  unsigned short* wproj = (unsigned short*)alloc(589824ull * 2);
  unsigned short* wfc1  = (unsigned short*)alloc(2359296ull * 2);
  unsigned short* wfc2  = (unsigned short*)alloc(2359296ull * 2);
  float* h3   = (float*)alloc(37632ull * 4);
  unsigned short* xln = (unsigned short*)alloc(9633792ull * 2);  // reused: att, h2
  float* maxn = (float*)alloc(12544ull * 4);
  float* aven = (float*)alloc(12544ull * 4);
  float* aveg = (float*)alloc(64ull * 4);
  float* s1   = (float*)alloc(12544ull * 4);
  float* gate = (float*)alloc(12544ull * 4);
  unsigned short* headsBase = (unsigned short*)alloc(4ull * 11010048ull * 2);  // q,k,v,vT; reused by fc1-out
  unsigned short* qg = headsBase;
  unsigned short* kg = headsBase + 11010048ull;
  unsigned short* vg = headsBase + 2ull * 11010048ull;
  unsigned short* vt = headsBase + 3ull * 11010048ull;
  unsigned short* att  = xln;
  unsigned short* h2   = xln;
  unsigned short* gbuf = headsBase;  // 12544*3072 bf16 fits in heads region
  float* x2 = out;                   // d_out doubles as x2 (proj writes, ln2/fc2 read, fc2 overwrites)

  cvt_kernel<<<dim3(1728), 256, 0, stream>>>(qkv_w, wqkv, 442368);
  cvt_kernel<<<dim3(576), 256, 0, stream>>>(proj_w, wproj, 147456);
  cvt_kernel<<<dim3(2304), 256, 0, stream>>>(fc1_w, wfc1, 589824);
  cvt_kernel<<<dim3(2304), 256, 0, stream>>>(fc2_w, wfc2, 589824);
  dwconv_kernel<<<dim3(192), 256, 0, stream>>>(xE, dw_w, dw_b, h3);
  ln1_kernel<<<dim3(12544), 256, 0, stream>>>(x, pos, ln1_s, ln1_b, xln, maxn, aven);
  gate1_kernel<<<dim3(64), 256, 0, stream>>>(maxn, aven, aveg, s1);
  gate2_kernel<<<dim3(196), 64, 0, stream>>>(aveg, aven, s1, gate);
  gemm_bt<M_QKV><<<dim3(98, 18), 256, 0, stream>>>(xln, wqkv, 768, 2304, nullptr, nullptr, nullptr,
      gate, h3, pw_w, pw_b, qg, kg, vg, vt, nullptr, nullptr);
  qkvpost_kernel<<<dim3(5376), 256, 0, stream>>>(qg, vg, vt);
  attn_kernel<<<dim3(512), 256, 0, stream>>>(qg, kg, vt, att);
  gemm_bt<M_PROJ><<<dim3(98, 6), 256, 0, stream>>>(att, wproj, 768, 768, proj_b, x, pos,
      nullptr, nullptr, nullptr, nullptr, nullptr, nullptr, nullptr, nullptr, x2, nullptr);
  ln2_kernel<<<dim3(12544), 256, 0, stream>>>(x2, ln2_s, ln2_b, h2);
  gemm_bt<M_GELU><<<dim3(98, 24), 256, 0, stream>>>(h2, wfc1, 768, 3072, fc1_b, nullptr, nullptr,
      nullptr, nullptr, nullptr, nullptr, nullptr, nullptr, nullptr, nullptr, nullptr, gbuf);
  gemm_bt<M_FC2><<<dim3(98, 6), 256, 0, stream>>>(gbuf, wfc2, 3072, 768, fc2_b, x2, nullptr,
      nullptr, nullptr, nullptr, nullptr, nullptr, nullptr, nullptr, nullptr, out, nullptr);
}

// Round 2
// 626.890 us; speedup vs baseline: 1.1094x; 1.1094x over previous
//
#include <hip/hip_runtime.h>

#define DEV __device__ __forceinline__

typedef __attribute__((ext_vector_type(8))) short short8_t;
typedef __attribute__((ext_vector_type(4))) float float4_t;
typedef __attribute__((ext_vector_type(4))) unsigned short ushort4_t;
typedef __attribute__((ext_vector_type(8))) unsigned short ushort8_t;

#define ATT_SCALE 0.10206207261596577f  // 96^-0.5

DEV unsigned short f2bf(float f) {
  unsigned u = __float_as_uint(f);
  u += 0x7fffu + ((u >> 16) & 1u);
  return (unsigned short)(u >> 16);
}
DEV float bf2f(unsigned short h) { return __uint_as_float(((unsigned)h) << 16); }

DEV float4_t mfma16(short8_t a, short8_t b, float4_t c) {
  return __builtin_amdgcn_mfma_f32_16x16x32_bf16(a, b, c, 0, 0, 0);
}

DEV void gl_lds16(const void* g, void* l) {
  __builtin_amdgcn_global_load_lds((__attribute__((address_space(1))) void*)g,
                                   (__attribute__((address_space(3))) void*)l, 16, 0, 0);
}

// ---------------------------------------------------------------- weight cvt (all 4 weights)
__global__ __launch_bounds__(256) void cvt_kernel(const float* __restrict__ w0,
    const float* __restrict__ w1, const float* __restrict__ w2, const float* __restrict__ w3,
    unsigned short* __restrict__ d0, unsigned short* __restrict__ d1,
    unsigned short* __restrict__ d2, unsigned short* __restrict__ d3) {
  const int i = blockIdx.x * 256 + threadIdx.x;  // < 1769472 float4 groups
  const float* s;
  unsigned short* d;
  int j;
  if (i < 442368) { s = w0; d = d0; j = i; }
  else if (i < 589824) { s = w1; d = d1; j = i - 442368; }
  else if (i < 1179648) { s = w2; d = d2; j = i - 589824; }
  else { s = w3; d = d3; j = i - 1179648; }
  float4_t v = ((const float4_t*)s)[j];
  ushort4_t o = {f2bf(v[0]), f2bf(v[1]), f2bf(v[2]), f2bf(v[3])};
  ((ushort4_t*)d)[j] = o;
}

// ---------------------------------------------------------------- depthwise conv
__global__ __launch_bounds__(256) void dwconv_kernel(const float* __restrict__ img,
    const float* __restrict__ wgt, const float* __restrict__ wb, float* __restrict__ h3) {
  __shared__ float wsm[256];
  const int bc = blockIdx.x;  // b*3+c
  const int c = bc % 3;
  const int tid = threadIdx.x;
  wsm[tid] = wgt[c * 256 + tid];
  __syncthreads();
  if (tid < 196) {
    const int ph = tid / 14, pwv = tid % 14;
    const float* ip = img + (size_t)bc * (222 * 222);
    float acc = 0.f;
#pragma unroll
    for (int i = 0; i < 16; ++i) {
      const int r = ph * 16 - 1 + i;
      if ((unsigned)r < 222u) {
        const float* rp = ip + r * 222;
#pragma unroll
        for (int j = 0; j < 16; ++j) {
          const int cc = pwv * 16 - 1 + j;
          if ((unsigned)cc < 222u) acc += rp[cc] * wsm[i * 16 + j];
        }
      }
    }
    h3[(size_t)bc * 196 + tid] = acc + wb[c];
  }
}

// ---------------------------------------------------------------- LN1 (+pos, +gate stats)
__global__ __launch_bounds__(256) void ln1_kernel(const float* __restrict__ x,
    const float* __restrict__ pos, const float* __restrict__ sG, const float* __restrict__ bG,
    unsigned short* __restrict__ xln, float* __restrict__ maxn, float* __restrict__ aven) {
  __shared__ float rA[4], rB[4], rC[4], rD[4];
  const int row = blockIdx.x, tid = threadIdx.x;
  const int n = row % 196;
  const float* xr = x + (size_t)row * 768;
  const float* pr = pos + (size_t)n * 768;
  float v0 = xr[tid] + pr[tid];
  float v1 = xr[tid + 256] + pr[tid + 256];
  float v2 = xr[tid + 512] + pr[tid + 512];
  float sm = v0 + v1 + v2;
  float sq = v0 * v0 + v1 * v1 + v2 * v2;
  for (int o = 32; o; o >>= 1) { sm += __shfl_xor(sm, o); sq += __shfl_xor(sq, o); }
  if ((tid & 63) == 0) { rA[tid >> 6] = sm; rB[tid >> 6] = sq; }
  __syncthreads();
  const float mean = (rA[0] + rA[1] + rA[2] + rA[3]) * (1.f / 768.f);
  const float var = (rB[0] + rB[1] + rB[2] + rB[3]) * (1.f / 768.f) - mean * mean;
  const float rstd = rsqrtf(var + 1e-5f);
  float y0 = (v0 - mean) * rstd * sG[tid] + bG[tid];
  float y1 = (v1 - mean) * rstd * sG[tid + 256] + bG[tid + 256];
  float y2 = (v2 - mean) * rstd * sG[tid + 512] + bG[tid + 512];
  unsigned short* xo = xln + (size_t)row * 768;
  xo[tid] = f2bf(y0); xo[tid + 256] = f2bf(y1); xo[tid + 512] = f2bf(y2);
  float mx = fmaxf(y0, fmaxf(y1, y2));
  float sy = y0 + y1 + y2;
  for (int o = 32; o; o >>= 1) { mx = fmaxf(mx, __shfl_xor(mx, o)); sy += __shfl_xor(sy, o); }
  if ((tid & 63) == 0) { rC[tid >> 6] = mx; rD[tid >> 6] = sy; }
  __syncthreads();
  if (tid == 0) {
    maxn[row] = fmaxf(fmaxf(rC[0], rC[1]), fmaxf(rC[2], rC[3]));
    aven[row] = (rD[0] + rD[1] + rD[2] + rD[3]) * (1.f / 768.f);
  }
}

// ---------------------------------------------------------------- LN2
__global__ __launch_bounds__(256) void ln2_kernel(const float* __restrict__ x2,
    const float* __restrict__ sG, const float* __restrict__ bG, unsigned short* __restrict__ h2) {
  __shared__ float rA[4], rB[4];
  const int row = blockIdx.x, tid = threadIdx.x;
  const float* xr = x2 + (size_t)row * 768;
  float v0 = xr[tid], v1 = xr[tid + 256], v2 = xr[tid + 512];
  float sm = v0 + v1 + v2;
  float sq = v0 * v0 + v1 * v1 + v2 * v2;
  for (int o = 32; o; o >>= 1) { sm += __shfl_xor(sm, o); sq += __shfl_xor(sq, o); }
  if ((tid & 63) == 0) { rA[tid >> 6] = sm; rB[tid >> 6] = sq; }
  __syncthreads();
  const float mean = (rA[0] + rA[1] + rA[2] + rA[3]) * (1.f / 768.f);
  const float var = (rB[0] + rB[1] + rB[2] + rB[3]) * (1.f / 768.f) - mean * mean;
  const float rstd = rsqrtf(var + 1e-5f);
  unsigned short* xo = h2 + (size_t)row * 768;
  xo[tid]       = f2bf((v0 - mean) * rstd * sG[tid] + bG[tid]);
  xo[tid + 256] = f2bf((v1 - mean) * rstd * sG[tid + 256] + bG[tid + 256]);
  xo[tid + 512] = f2bf((v2 - mean) * rstd * sG[tid + 512] + bG[tid + 512]);
}

// ---------------------------------------------------------------- gate
__global__ __launch_bounds__(256) void gate1_kernel(const float* __restrict__ maxn,
    const float* __restrict__ aven, float* __restrict__ aveg, float* __restrict__ s1) {
  __shared__ float rA[4], rB[4], rC[4], rD[4];
  const int b = blockIdx.x, tid = threadIdx.x;
  const bool ok = tid < 196;
  const float mv = ok ? maxn[b * 196 + tid] : -1e30f;
  const float av = ok ? aven[b * 196 + tid] : 0.f;
  float m = mv, sa = av;
  for (int o = 32; o; o >>= 1) { m = fmaxf(m, __shfl_xor(m, o)); sa += __shfl_xor(sa, o); }
  if ((tid & 63) == 0) { rA[tid >> 6] = m; rB[tid >> 6] = sa; }
  __syncthreads();
  const float maxg = fmaxf(fmaxf(rA[0], rA[1]), fmaxf(rA[2], rA[3]));
  const float avg = (rB[0] + rB[1] + rB[2] + rB[3]) * (1.f / 196.f);
  if (tid == 0) aveg[b] = avg;
  const float t1 = ok ? maxg * mv : -1e30f;
  float m2 = t1;
  for (int o = 32; o; o >>= 1) m2 = fmaxf(m2, __shfl_xor(m2, o));
  if ((tid & 63) == 0) rC[tid >> 6] = m2;
  __syncthreads();
  const float m2g = fmaxf(fmaxf(rC[0], rC[1]), fmaxf(rC[2], rC[3]));
  const float e = ok ? __expf(t1 - m2g) : 0.f;
  float se = e;
  for (int o = 32; o; o >>= 1) se += __shfl_xor(se, o);
  if ((tid & 63) == 0) rD[tid >> 6] = se;
  __syncthreads();
  const float seg = rD[0] + rD[1] + rD[2] + rD[3];
  if (ok) s1[b * 196 + tid] = e / seg;
}

__global__ __launch_bounds__(64) void gate2_kernel(const float* __restrict__ aveg,
    const float* __restrict__ aven, const float* __restrict__ s1, float* __restrict__ gate) {
  const int n = blockIdx.x, bb = threadIdx.x;  // bb = batch index, 64 lanes
  const float t2 = aveg[bb] * aven[bb * 196 + n];
  float m = t2;
  for (int o = 32; o; o >>= 1) m = fmaxf(m, __shfl_xor(m, o));
  const float e = __expf(t2 - m);
  float ssum = e;
  for (int o = 32; o; o >>= 1) ssum += __shfl_xor(ssum, o);
  gate[bb * 196 + n] = s1[bb * 196 + n] * e / ssum;
}

// ---------------------------------------------------------------- GEMM (A @ W^T)
// C^T-register form: acc[mi][ni][r] = C[m = m0+wm+mi*16+l15][n = n0+wn+ni*16+quad*4+r]
enum { M_QKV = 0, M_PROJ = 1, M_GELU = 2, M_FC2 = 3 };

template <int MODE>
__global__ __launch_bounds__(256, 2) void gemm_bt(
    const unsigned short* __restrict__ A, const unsigned short* __restrict__ W,
    int K, int Nd,
    const float* __restrict__ bias,
    const float* __restrict__ res0, const float* __restrict__ res1,
    const float* __restrict__ gate, const float* __restrict__ h3,
    const float* __restrict__ pw, const float* __restrict__ pwb,
    unsigned short* __restrict__ oQ, unsigned short* __restrict__ oK,
    unsigned short* __restrict__ oV,
    float* __restrict__ oF, unsigned short* __restrict__ oB) {
  __shared__ __align__(16) unsigned short smem[8192];  // A rows 0-127 [0,8192)B, B [8192,16384)B
  const int tid = threadIdx.x;
  const int w = tid >> 6, lane = tid & 63;
  const int l15 = lane & 15, quad = lane >> 4;
  const int n0 = blockIdx.x * 128, m0 = blockIdx.y * 128;  // n fastest: A-panel reuse in L2

  const int row0 = tid >> 2;
  const int kc = (((tid & 3) ^ ((tid >> 3) & 3)) << 3);  // XOR-swizzled k-chunk
  const size_t arow0 = (size_t)(m0 + row0) * K + kc;
  const size_t arow1 = (size_t)(m0 + 64 + row0) * K + kc;
  const size_t brow0 = (size_t)(n0 + row0) * K + kc;
  const size_t brow1 = (size_t)(n0 + 64 + row0) * K + kc;
  char* sb = (char*)smem;
  const int ldsA0 = w * 1024, ldsA1 = 4096 + w * 1024;
  const int ldsB0 = 8192 + w * 1024, ldsB1 = 12288 + w * 1024;

  float4_t acc[4][4];
#pragma unroll
  for (int i = 0; i < 4; ++i)
#pragma unroll
    for (int j = 0; j < 4; ++j) acc[i][j] = (float4_t){0.f, 0.f, 0.f, 0.f};

  const int wm = (w >> 1) << 6, wn = (w & 1) << 6;
  const unsigned short* as_ = smem;
  const unsigned short* bs_ = smem + 4096;
  const int squad = quad ^ ((l15 >> 1) & 3);  // matches staging swizzle; 2-way banks

  for (int kt = 0; kt < K; kt += 32) {
    gl_lds16(A + arow0 + kt, sb + ldsA0);
    gl_lds16(A + arow1 + kt, sb + ldsA1);
    gl_lds16(W + brow0 + kt, sb + ldsB0);
    gl_lds16(W + brow1 + kt, sb + ldsB1);
    __syncthreads();
    short8_t af[4], bfr[4];
#pragma unroll
    for (int mi = 0; mi < 4; ++mi)
      af[mi] = *(const short8_t*)(as_ + (wm + mi * 16 + l15) * 32 + squad * 8);
#pragma unroll
    for (int ni = 0; ni < 4; ++ni)
      bfr[ni] = *(const short8_t*)(bs_ + (wn + ni * 16 + l15) * 32 + squad * 8);
#pragma unroll
    for (int mi = 0; mi < 4; ++mi)
#pragma unroll
      for (int ni = 0; ni < 4; ++ni)
        acc[mi][ni] = mfma16(bfr[ni], af[mi], acc[mi][ni]);  // C^T layout
    __syncthreads();
  }

  if (MODE == M_QKV) {
    const int sel = n0 / 768;  // block-uniform: 0=q 1=k 2=v
    unsigned short* dst = (sel == 0) ? oQ : (sel == 1) ? oK : oV;
    const int nb = n0 - sel * 768 + wn;
#pragma unroll
    for (int mi = 0; mi < 4; ++mi) {
      const int m = m0 + wm + mi * 16 + l15;
      float gv = 0.f, h30 = 0.f, h31 = 0.f, h32 = 0.f;
      if (sel == 2) {
        const int b = m / 196, n = m - b * 196;
        gv = gate[m];
        h30 = h3[(b * 3 + 0) * 196 + n];
        h31 = h3[(b * 3 + 1) * 196 + n];
        h32 = h3[(b * 3 + 2) * 196 + n];
      }
      unsigned short* orow = dst + (size_t)m * 768;
#pragma unroll
      for (int ni = 0; ni < 4; ++ni) {
        const int dcol = nb + ni * 16 + quad * 4;
        ushort4_t st;
        if (sel == 2) {
          const float4_t pwf0 = *(const float4_t*)(pw + dcol * 3);
          const float4_t pwf1 = *(const float4_t*)(pw + dcol * 3 + 4);
          const float4_t pwf2 = *(const float4_t*)(pw + dcol * 3 + 8);
          const float4_t pbf = *(const float4_t*)(pwb + dcol);
          float pwflat[12] = {pwf0[0], pwf0[1], pwf0[2], pwf0[3], pwf1[0], pwf1[1],
                              pwf1[2], pwf1[3], pwf2[0], pwf2[1], pwf2[2], pwf2[3]};
#pragma unroll
          for (int r = 0; r < 4; ++r) {
            const float v = acc[mi][ni][r] * gv + h30 * pwflat[3 * r] +
                            h31 * pwflat[3 * r + 1] + h32 * pwflat[3 * r + 2] + pbf[r];
            st[r] = f2bf(v);
          }
        } else {
#pragma unroll
          for (int r = 0; r < 4; ++r) st[r] = f2bf(acc[mi][ni][r]);
        }
        *(ushort4_t*)(orow + dcol) = st;
      }
    }
  } else if (MODE == M_PROJ || MODE == M_FC2) {
#pragma unroll
    for (int mi = 0; mi < 4; ++mi) {
      const int m = m0 + wm + mi * 16 + l15;
      const int nseq = m % 196;
      const float* rr0 = res0 + (size_t)m * 768;
      const float* rr1 = (MODE == M_PROJ) ? res1 + (size_t)nseq * 768 : nullptr;
      float* oo = oF + (size_t)m * 768;
#pragma unroll
      for (int ni = 0; ni < 4; ++ni) {
        const int col = n0 + wn + ni * 16 + quad * 4;
        const float4_t bb = *(const float4_t*)(bias + col);
        const float4_t r0v = *(const float4_t*)(rr0 + col);
        float4_t v;
#pragma unroll
        for (int r = 0; r < 4; ++r) v[r] = acc[mi][ni][r] + bb[r] + r0v[r];
        if (MODE == M_PROJ) {
          const float4_t r1v = *(const float4_t*)(rr1 + col);
#pragma unroll
          for (int r = 0; r < 4; ++r) v[r] += r1v[r];
        }
        *(float4_t*)(oo + col) = v;
      }
    }
  } else {  // M_GELU
#pragma unroll
    for (int mi = 0; mi < 4; ++mi) {
      const int m = m0 + wm + mi * 16 + l15;
      unsigned short* oo = oB + (size_t)m * Nd;
#pragma unroll
      for (int ni = 0; ni < 4; ++ni) {
        const int col = n0 + wn + ni * 16 + quad * 4;
        const float4_t bb = *(const float4_t*)(bias + col);
        ushort4_t st;
#pragma unroll
        for (int r = 0; r < 4; ++r) {
          const float t = acc[mi][ni][r] + bb[r];
          st[r] = f2bf(0.5f * t * (1.f + erff(t * 0.70710678118654752f)));
        }
        *(ushort4_t*)(oo + col) = st;
      }
    }
  }
}

// ---------------------------------------------------------------- V transpose: (b,n,h*96+d) -> (b,h,d,n224)
__global__ __launch_bounds__(256) void vtrans_kernel(const unsigned short* __restrict__ vg,
                                                     unsigned short* __restrict__ vt) {
  __shared__ unsigned short lds[96 * 226];
  const int bh = blockIdx.x, b = bh >> 3, h = bh & 7;
  const int tid = threadIdx.x;
  const unsigned short* base = vg + (size_t)(b * 196) * 768 + h * 96;
  for (int idx = tid; idx < 196 * 12; idx += 256) {
    const int n = idx / 12, c = idx % 12;
    const ushort8_t rv = *(const ushort8_t*)(base + (size_t)n * 768 + c * 8);
#pragma unroll
    for (int j = 0; j < 8; ++j) lds[(c * 8 + j) * 226 + n] = rv[j];
  }
  __syncthreads();
  unsigned short* ob = vt + (size_t)bh * (96 * 224);
  for (int idx = tid; idx < 96 * 28; idx += 256) {
    const int d = idx / 28, c = idx % 28;
    const int nn = c * 8;
    ushort8_t o;
#pragma unroll
    for (int j = 0; j < 8; ++j) o[j] = (nn + j < 196) ? lds[d * 226 + nn + j] : (unsigned short)0;
    *(ushort8_t*)(ob + (size_t)d * 224 + nn) = o;
  }
}

// ---------------------------------------------------------------- fused attention
__global__ __launch_bounds__(256, 2) void attn_kernel(
    const unsigned short* __restrict__ qg, const unsigned short* __restrict__ vg,
    const unsigned short* __restrict__ kg, const unsigned short* __restrict__ vt,
    unsigned short* __restrict__ att) {
  __shared__ __align__(16) unsigned short p_s[4][16][232];
  const int bh = blockIdx.x, b = bh >> 3, h = bh & 7;
  const int tid = threadIdx.x, w = tid >> 6, lane = tid & 63;
  const int l15 = lane & 15, quad = lane >> 4;
  const unsigned short* qb = qg + (size_t)(b * 196) * 768 + h * 96;
  const unsigned short* vb = vg + (size_t)(b * 196) * 768 + h * 96;
  const unsigned short* kb = kg + (size_t)(b * 196) * 768 + h * 96;
  const unsigned short* vtb = vt + (size_t)bh * (96 * 224);
  for (int i = lane; i < 256; i += 64) p_s[w][i >> 4][208 + (i & 15)] = 0;

  for (int qt = w; qt < 13; qt += 4) {
    const size_t qoff = (size_t)(qt * 16 + l15) * 768 + quad * 8;
    short8_t a0, a1, a2;
    {
      const ushort8_t q0 = *(const ushort8_t*)(qb + qoff);
      const ushort8_t q1 = *(const ushort8_t*)(qb + qoff + 32);
      const ushort8_t q2 = *(const ushort8_t*)(qb + qoff + 64);
      const ushort8_t v0 = *(const ushort8_t*)(vb + qoff);
      const ushort8_t v1 = *(const ushort8_t*)(vb + qoff + 32);
      const ushort8_t v2 = *(const ushort8_t*)(vb + qoff + 64);
#pragma unroll
      for (int j = 0; j < 8; ++j) {
        a0[j] = (short)f2bf(bf2f(q0[j]) + bf2f(v0[j]));
        a1[j] = (short)f2bf(bf2f(q1[j]) + bf2f(v1[j]));
        a2[j] = (short)f2bf(bf2f(q2[j]) + bf2f(v2[j]));
      }
    }
    float4_t S[13];
#pragma unroll
    for (int c = 0; c < 13; ++c) S[c] = (float4_t){0.f, 0.f, 0.f, 0.f};
#pragma unroll
    for (int c = 0; c < 13; ++c) {
      const unsigned short* kr = kb + (size_t)(c * 16 + l15) * 768 + quad * 8;
      S[c] = mfma16(a0, *(const short8_t*)(kr), S[c]);
      S[c] = mfma16(a1, *(const short8_t*)(kr + 32), S[c]);
      S[c] = mfma16(a2, *(const short8_t*)(kr + 64), S[c]);
    }
    float mx[4] = {-1e30f, -1e30f, -1e30f, -1e30f};
#pragma unroll
    for (int c = 0; c < 13; ++c) {
      const bool okc = (c * 16 + l15) < 196;
#pragma unroll
      for (int r = 0; r < 4; ++r) {
        const float v = S[c][r] * ATT_SCALE;
        S[c][r] = okc ? v : -1e30f;
        mx[r] = fmaxf(mx[r], S[c][r]);
      }
    }
#pragma unroll
    for (int o = 1; o <= 8; o <<= 1)
#pragma unroll
      for (int r = 0; r < 4; ++r) mx[r] = fmaxf(mx[r], __shfl_xor(mx[r], o));
    float sum[4] = {0.f, 0.f, 0.f, 0.f};
#pragma unroll
    for (int c = 0; c < 13; ++c)
#pragma unroll
      for (int r = 0; r < 4; ++r) {
        const float e = __expf(S[c][r] - mx[r]);
        S[c][r] = e;
        sum[r] += e;
      }
#pragma unroll
    for (int o = 1; o <= 8; o <<= 1)
#pragma unroll
      for (int r = 0; r < 4; ++r) sum[r] += __shfl_xor(sum[r], o);
    float inv[4];
#pragma unroll
    for (int r = 0; r < 4; ++r) inv[r] = 1.f / sum[r];
#pragma unroll
    for (int c = 0; c < 13; ++c)
#pragma unroll
      for (int r = 0; r < 4; ++r)
        p_s[w][quad * 4 + r][c * 16 + l15] = f2bf(S[c][r] * inv[r]);

    // O^T form: O[ni][r] -> d = ni*16+quad*4+r, q-row m = qt*16+l15
    float4_t O[6];
#pragma unroll
    for (int ni = 0; ni < 6; ++ni) O[ni] = (float4_t){0.f, 0.f, 0.f, 0.f};
#pragma unroll
    for (int s = 0; s < 7; ++s) {
      short8_t pa = *(const short8_t*)(&p_s[w][l15][s * 32 + quad * 8]);
#pragma unroll
      for (int ni = 0; ni < 6; ++ni) {
        short8_t vf = *(const short8_t*)(vtb + (size_t)(ni * 16 + l15) * 224 + s * 32 + quad * 8);
        O[ni] = mfma16(vf, pa, O[ni]);
      }
    }
    const int m = qt * 16 + l15;
    if (m < 196) {
      unsigned short* ar = att + (size_t)(b * 196 + m) * 768 + h * 96 + quad * 4;
#pragma unroll
      for (int ni = 0; ni < 6; ++ni) {
        ushort4_t st = {f2bf(O[ni][0]), f2bf(O[ni][1]), f2bf(O[ni][2]), f2bf(O[ni][3])};
        *(ushort4_t*)(ar + ni * 16) = st;
      }
    }
  }
}

// ---------------------------------------------------------------- launch
extern "C" void kernel_launch(void* const* d_in, const int* in_sizes, int n_in,
                              void* d_out, int out_size, void* d_ws, size_t ws_size,
                              hipStream_t stream) {
  (void)in_sizes; (void)n_in; (void)out_size; (void)ws_size;
  const float* x      = (const float*)d_in[0];
  const float* xE     = (const float*)d_in[1];
  const float* pos    = (const float*)d_in[2];
  const float* dw_w   = (const float*)d_in[3];
  const float* dw_b   = (const float*)d_in[4];
  const float* pw_w   = (const float*)d_in[5];
  const float* pw_b   = (const float*)d_in[6];
  const float* qkv_w  = (const float*)d_in[7];
  const float* proj_w = (const float*)d_in[8];
  const float* proj_b = (const float*)d_in[9];
  const float* ln1_s  = (const float*)d_in[10];
  const float* ln1_b  = (const float*)d_in[11];
  const float* ln2_s  = (const float*)d_in[12];
  const float* ln2_b  = (const float*)d_in[13];
  const float* fc1_w  = (const float*)d_in[14];
  const float* fc1_b  = (const float*)d_in[15];
  const float* fc2_w  = (const float*)d_in[16];
  const float* fc2_b  = (const float*)d_in[17];
  float* out = (float*)d_out;

  char* ws = (char*)d_ws;
  size_t off = 0;
  auto alloc = [&](size_t bytes) -> void* {
    void* p = ws + off;
    off += (bytes + 255) & ~(size_t)255;
    return p;
  };
  unsigned short* wqkv  = (unsigned short*)alloc(1769472ull * 2);
  unsigned short* wproj = (unsigned short*)alloc(589824ull * 2);
  unsigned short* wfc1  = (unsigned short*)alloc(2359296ull * 2);
  unsigned short* wfc2  = (unsigned short*)alloc(2359296ull * 2);
  float* h3   = (float*)alloc(37632ull * 4);
  unsigned short* xln = (unsigned short*)alloc(9633792ull * 2);  // reused: att, h2
  float* maxn = (float*)alloc(12544ull * 4);
  float* aven = (float*)alloc(12544ull * 4);
  float* aveg = (float*)alloc(64ull * 4);
  float* s1   = (float*)alloc(12544ull * 4);
  float* gate = (float*)alloc(12544ull * 4);
  // big region: q,k,v ((12544+16) rows x 768) + vt (512*96*224); reused by gbuf (12544*3072)
  const size_t ROWP = 9646080ull;  // (12544+16)*768
  unsigned short* big = (unsigned short*)alloc((3ull * ROWP + 11010048ull) * 2);
  unsigned short* qg = big;
  unsigned short* kg = big + ROWP;
  unsigned short* vg = big + 2ull * ROWP;
  unsigned short* vt = big + 3ull * ROWP;
  unsigned short* att  = xln;
  unsigned short* h2   = xln;
  unsigned short* gbuf = big;  // 12544*3072 = 38.5M u16 < 39.9M region
  float* x2 = out;             // d_out doubles as x2

  cvt_kernel<<<dim3(6912), 256, 0, stream>>>(qkv_w, proj_w, fc1_w, fc2_w, wqkv, wproj, wfc1, wfc2);
  dwconv_kernel<<<dim3(192), 256, 0, stream>>>(xE, dw_w, dw_b, h3);
  ln1_kernel<<<dim3(12544), 256, 0, stream>>>(x, pos, ln1_s, ln1_b, xln, maxn, aven);
  gate1_kernel<<<dim3(64), 256, 0, stream>>>(maxn, aven, aveg, s1);
  gate2_kernel<<<dim3(196), 64, 0, stream>>>(aveg, aven, s1, gate);
  gemm_bt<M_QKV><<<dim3(18, 98), 256, 0, stream>>>(xln, wqkv, 768, 2304, nullptr, nullptr, nullptr,
      gate, h3, pw_w, pw_b, qg, kg, vg, nullptr, nullptr);
  vtrans_kernel<<<dim3(512), 256, 0, stream>>>(vg, vt);
  attn_kernel<<<dim3(512), 256, 0, stream>>>(qg, vg, kg, vt, att);
  gemm_bt<M_PROJ><<<dim3(6, 98), 256, 0, stream>>>(att, wproj, 768, 768, proj_b, x, pos,
      nullptr, nullptr, nullptr, nullptr, nullptr, nullptr, nullptr, x2, nullptr);
  ln2_kernel<<<dim3(12544), 256, 0, stream>>>(x2, ln2_s, ln2_b, h2);
  gemm_bt<M_GELU><<<dim3(24, 98), 256, 0, stream>>>(h2, wfc1, 768, 3072, fc1_b, nullptr, nullptr,
      nullptr, nullptr, nullptr, nullptr, nullptr, nullptr, nullptr, nullptr, gbuf);
  gemm_bt<M_FC2><<<dim3(6, 98), 256, 0, stream>>>(gbuf, wfc2, 3072, 768, fc2_b, x2, nullptr,
      nullptr, nullptr, nullptr, nullptr, nullptr, nullptr, nullptr, out, nullptr);
}

// Round 3
// 520.307 us; speedup vs baseline: 1.3366x; 1.2048x over previous
//
#include <hip/hip_runtime.h>

#define DEV __device__ __forceinline__

typedef __attribute__((ext_vector_type(8))) short short8_t;
typedef __attribute__((ext_vector_type(4))) float float4_t;
typedef __attribute__((ext_vector_type(4))) unsigned short ushort4_t;
typedef __attribute__((ext_vector_type(8))) unsigned short ushort8_t;

#define ATT_SCALE 0.10206207261596577f  // 96^-0.5

DEV unsigned short f2bf(float f) {
  unsigned u = __float_as_uint(f);
  u += 0x7fffu + ((u >> 16) & 1u);
  return (unsigned short)(u >> 16);
}
DEV float bf2f(unsigned short h) { return __uint_as_float(((unsigned)h) << 16); }

DEV float4_t mfma16(short8_t a, short8_t b, float4_t c) {
  return __builtin_amdgcn_mfma_f32_16x16x32_bf16(a, b, c, 0, 0, 0);
}

DEV void gl_lds16(const void* g, void* l) {
  __builtin_amdgcn_global_load_lds((__attribute__((address_space(1))) void*)g,
                                   (__attribute__((address_space(3))) void*)l, 16, 0, 0);
}

// ---------------------------------------------------------------- weight cvt (all 4 weights)
__global__ __launch_bounds__(256) void cvt_kernel(const float* __restrict__ w0,
    const float* __restrict__ w1, const float* __restrict__ w2, const float* __restrict__ w3,
    unsigned short* __restrict__ d0, unsigned short* __restrict__ d1,
    unsigned short* __restrict__ d2, unsigned short* __restrict__ d3) {
  const int i = blockIdx.x * 256 + threadIdx.x;  // < 1769472 float4 groups
  const float* s;
  unsigned short* d;
  int j;
  if (i < 442368) { s = w0; d = d0; j = i; }
  else if (i < 589824) { s = w1; d = d1; j = i - 442368; }
  else if (i < 1179648) { s = w2; d = d2; j = i - 589824; }
  else { s = w3; d = d3; j = i - 1179648; }
  float4_t v = ((const float4_t*)s)[j];
  ushort4_t o = {f2bf(v[0]), f2bf(v[1]), f2bf(v[2]), f2bf(v[3])};
  ((ushort4_t*)d)[j] = o;
}

// ---------------------------------------------------------------- depthwise conv
__global__ __launch_bounds__(256) void dwconv_kernel(const float* __restrict__ img,
    const float* __restrict__ wgt, const float* __restrict__ wb, float* __restrict__ h3) {
  __shared__ float wsm[256];
  const int bc = blockIdx.x;  // b*3+c
  const int c = bc % 3;
  const int tid = threadIdx.x;
  wsm[tid] = wgt[c * 256 + tid];
  __syncthreads();
  if (tid < 196) {
    const int ph = tid / 14, pwv = tid % 14;
    const float* ip = img + (size_t)bc * (222 * 222);
    float acc = 0.f;
#pragma unroll
    for (int i = 0; i < 16; ++i) {
      const int r = ph * 16 - 1 + i;
      if ((unsigned)r < 222u) {
        const float* rp = ip + r * 222;
#pragma unroll
        for (int j = 0; j < 16; ++j) {
          const int cc = pwv * 16 - 1 + j;
          if ((unsigned)cc < 222u) acc += rp[cc] * wsm[i * 16 + j];
        }
      }
    }
    h3[(size_t)bc * 196 + tid] = acc + wb[c];
  }
}

// ---------------------------------------------------------------- LN1 (+pos, +gate stats)
__global__ __launch_bounds__(256) void ln1_kernel(const float* __restrict__ x,
    const float* __restrict__ pos, const float* __restrict__ sG, const float* __restrict__ bG,
    unsigned short* __restrict__ xln, float* __restrict__ maxn, float* __restrict__ aven) {
  __shared__ float rA[4], rB[4], rC[4], rD[4];
  const int row = blockIdx.x, tid = threadIdx.x;
  const int n = row % 196;
  const float* xr = x + (size_t)row * 768;
  const float* pr = pos + (size_t)n * 768;
  float v0 = xr[tid] + pr[tid];
  float v1 = xr[tid + 256] + pr[tid + 256];
  float v2 = xr[tid + 512] + pr[tid + 512];
  float sm = v0 + v1 + v2;
  float sq = v0 * v0 + v1 * v1 + v2 * v2;
  for (int o = 32; o; o >>= 1) { sm += __shfl_xor(sm, o); sq += __shfl_xor(sq, o); }
  if ((tid & 63) == 0) { rA[tid >> 6] = sm; rB[tid >> 6] = sq; }
  __syncthreads();
  const float mean = (rA[0] + rA[1] + rA[2] + rA[3]) * (1.f / 768.f);
  const float var = (rB[0] + rB[1] + rB[2] + rB[3]) * (1.f / 768.f) - mean * mean;
  const float rstd = rsqrtf(var + 1e-5f);
  float y0 = (v0 - mean) * rstd * sG[tid] + bG[tid];
  float y1 = (v1 - mean) * rstd * sG[tid + 256] + bG[tid + 256];
  float y2 = (v2 - mean) * rstd * sG[tid + 512] + bG[tid + 512];
  unsigned short* xo = xln + (size_t)row * 768;
  xo[tid] = f2bf(y0); xo[tid + 256] = f2bf(y1); xo[tid + 512] = f2bf(y2);
  float mx = fmaxf(y0, fmaxf(y1, y2));
  float sy = y0 + y1 + y2;
  for (int o = 32; o; o >>= 1) { mx = fmaxf(mx, __shfl_xor(mx, o)); sy += __shfl_xor(sy, o); }
  if ((tid & 63) == 0) { rC[tid >> 6] = mx; rD[tid >> 6] = sy; }
  __syncthreads();
  if (tid == 0) {
    maxn[row] = fmaxf(fmaxf(rC[0], rC[1]), fmaxf(rC[2], rC[3]));
    aven[row] = (rD[0] + rD[1] + rD[2] + rD[3]) * (1.f / 768.f);
  }
}

// ---------------------------------------------------------------- LN2
__global__ __launch_bounds__(256) void ln2_kernel(const float* __restrict__ x2,
    const float* __restrict__ sG, const float* __restrict__ bG, unsigned short* __restrict__ h2) {
  __shared__ float rA[4], rB[4];
  const int row = blockIdx.x, tid = threadIdx.x;
  const float* xr = x2 + (size_t)row * 768;
  float v0 = xr[tid], v1 = xr[tid + 256], v2 = xr[tid + 512];
  float sm = v0 + v1 + v2;
  float sq = v0 * v0 + v1 * v1 + v2 * v2;
  for (int o = 32; o; o >>= 1) { sm += __shfl_xor(sm, o); sq += __shfl_xor(sq, o); }
  if ((tid & 63) == 0) { rA[tid >> 6] = sm; rB[tid >> 6] = sq; }
  __syncthreads();
  const float mean = (rA[0] + rA[1] + rA[2] + rA[3]) * (1.f / 768.f);
  const float var = (rB[0] + rB[1] + rB[2] + rB[3]) * (1.f / 768.f) - mean * mean;
  const float rstd = rsqrtf(var + 1e-5f);
  unsigned short* xo = h2 + (size_t)row * 768;
  xo[tid]       = f2bf((v0 - mean) * rstd * sG[tid] + bG[tid]);
  xo[tid + 256] = f2bf((v1 - mean) * rstd * sG[tid + 256] + bG[tid + 256]);
  xo[tid + 512] = f2bf((v2 - mean) * rstd * sG[tid + 512] + bG[tid + 512]);
}

// ---------------------------------------------------------------- gate
__global__ __launch_bounds__(256) void gate1_kernel(const float* __restrict__ maxn,
    const float* __restrict__ aven, float* __restrict__ aveg, float* __restrict__ s1) {
  __shared__ float rA[4], rB[4], rC[4], rD[4];
  const int b = blockIdx.x, tid = threadIdx.x;
  const bool ok = tid < 196;
  const float mv = ok ? maxn[b * 196 + tid] : -1e30f;
  const float av = ok ? aven[b * 196 + tid] : 0.f;
  float m = mv, sa = av;
  for (int o = 32; o; o >>= 1) { m = fmaxf(m, __shfl_xor(m, o)); sa += __shfl_xor(sa, o); }
  if ((tid & 63) == 0) { rA[tid >> 6] = m; rB[tid >> 6] = sa; }
  __syncthreads();
  const float maxg = fmaxf(fmaxf(rA[0], rA[1]), fmaxf(rA[2], rA[3]));
  const float avg = (rB[0] + rB[1] + rB[2] + rB[3]) * (1.f / 196.f);
  if (tid == 0) aveg[b] = avg;
  const float t1 = ok ? maxg * mv : -1e30f;
  float m2 = t1;
  for (int o = 32; o; o >>= 1) m2 = fmaxf(m2, __shfl_xor(m2, o));
  if ((tid & 63) == 0) rC[tid >> 6] = m2;
  __syncthreads();
  const float m2g = fmaxf(fmaxf(rC[0], rC[1]), fmaxf(rC[2], rC[3]));
  const float e = ok ? __expf(t1 - m2g) : 0.f;
  float se = e;
  for (int o = 32; o; o >>= 1) se += __shfl_xor(se, o);
  if ((tid & 63) == 0) rD[tid >> 6] = se;
  __syncthreads();
  const float seg = rD[0] + rD[1] + rD[2] + rD[3];
  if (ok) s1[b * 196 + tid] = e / seg;
}

__global__ __launch_bounds__(64) void gate2_kernel(const float* __restrict__ aveg,
    const float* __restrict__ aven, const float* __restrict__ s1, float* __restrict__ gate) {
  const int n = blockIdx.x, bb = threadIdx.x;  // bb = batch index, 64 lanes
  const float t2 = aveg[bb] * aven[bb * 196 + n];
  float m = t2;
  for (int o = 32; o; o >>= 1) m = fmaxf(m, __shfl_xor(m, o));
  const float e = __expf(t2 - m);
  float ssum = e;
  for (int o = 32; o; o >>= 1) ssum += __shfl_xor(ssum, o);
  gate[bb * 196 + n] = s1[bb * 196 + n] * e / ssum;
}

// ---------------------------------------------------------------- GEMM (A @ W^T), BK=64, XCD-banded
// C^T-register form: acc[mi][ni][r] = C[m = m0+wm+mi*16+l15][n = n0+wn+ni*16+quad*4+r]
enum { M_QKV = 0, M_PROJ = 1, M_GELU = 2, M_FC2 = 3 };

template <int MODE>
__global__ __launch_bounds__(256, 2) void gemm_bt(
    const unsigned short* __restrict__ A, const unsigned short* __restrict__ W,
    int K, int Nd, int NT, int T,
    const float* __restrict__ bias,
    const float* __restrict__ res0, const float* __restrict__ res1,
    const float* __restrict__ gate, const float* __restrict__ h3,
    const float* __restrict__ pw, const float* __restrict__ pwb,
    unsigned short* __restrict__ oQ, unsigned short* __restrict__ oK,
    unsigned short* __restrict__ oV,
    float* __restrict__ oF, unsigned short* __restrict__ oB) {
  __shared__ __align__(16) unsigned short smem[16384];  // A [0,16K)B, B [16K,32K)B; rows of 128B
  // XCD-banded tile mapping: xcd = blk&7 owns contiguous m-band, n-fastest within it
  const int l = blockIdx.x;
  const int xc = l & 7, kb = l >> 3;
  const int tbase = (xc * T) >> 3;
  if (kb >= (((xc + 1) * T) >> 3) - tbase) return;
  const int t = tbase + kb;
  const int mt = t / NT, nt = t - mt * NT;
  const int m0 = mt * 128, n0 = nt * 128;

  const int tid = threadIdx.x;
  const int w = tid >> 6, lane = tid & 63;
  const int l15 = lane & 15, quad = lane >> 4;

  // staging: per (w, call j): 8 rows x 128B; lane -> row base + lane/8, dest chunk lane&7
  const int srow = w * 8 + (lane >> 3);
  const int cs = (lane & 7) ^ (lane >> 3);  // source chunk (XOR swizzle vs dest)
  size_t aoff[4], boff[4];
#pragma unroll
  for (int j = 0; j < 4; ++j) {
    aoff[j] = (size_t)(m0 + j * 32 + srow) * K + cs * 8;
    boff[j] = (size_t)(n0 + j * 32 + srow) * K + cs * 8;
  }
  char* sb = (char*)smem;

  float4_t acc[4][4];
#pragma unroll
  for (int i = 0; i < 4; ++i)
#pragma unroll
    for (int j = 0; j < 4; ++j) acc[i][j] = (float4_t){0.f, 0.f, 0.f, 0.f};

  const int wm = (w >> 1) << 6, wn = (w & 1) << 6;
  const unsigned short* as_ = smem;
  const unsigned short* bs_ = smem + 8192;
  const int rx = l15 & 7;  // row&7 for frag rows

  for (int kt = 0; kt < K; kt += 64) {
#pragma unroll
    for (int j = 0; j < 4; ++j) gl_lds16(A + aoff[j] + kt, sb + j * 4096 + w * 1024);
#pragma unroll
    for (int j = 0; j < 4; ++j) gl_lds16(W + boff[j] + kt, sb + 16384 + j * 4096 + w * 1024);
    __syncthreads();
#pragma unroll
    for (int h = 0; h < 2; ++h) {
      const int ch = (quad + 4 * h) ^ rx;
      short8_t af[4], bfr[4];
#pragma unroll
      for (int mi = 0; mi < 4; ++mi)
        af[mi] = *(const short8_t*)(as_ + (wm + mi * 16 + l15) * 64 + ch * 8);
#pragma unroll
      for (int ni = 0; ni < 4; ++ni)
        bfr[ni] = *(const short8_t*)(bs_ + (wn + ni * 16 + l15) * 64 + ch * 8);
#pragma unroll
      for (int mi = 0; mi < 4; ++mi)
#pragma unroll
        for (int ni = 0; ni < 4; ++ni)
          acc[mi][ni] = mfma16(bfr[ni], af[mi], acc[mi][ni]);  // C^T layout
    }
    __syncthreads();
  }

  if (MODE == M_QKV) {
    const int sel = n0 / 768;  // block-uniform: 0=q 1=k 2=v
    unsigned short* dst = (sel == 0) ? oQ : (sel == 1) ? oK : oV;
    const int nb = n0 - sel * 768 + wn;
#pragma unroll
    for (int mi = 0; mi < 4; ++mi) {
      const int m = m0 + wm + mi * 16 + l15;
      float gv = 0.f, h30 = 0.f, h31 = 0.f, h32 = 0.f;
      if (sel == 2) {
        const int b = m / 196, n = m - b * 196;
        gv = gate[m];
        h30 = h3[(b * 3 + 0) * 196 + n];
        h31 = h3[(b * 3 + 1) * 196 + n];
        h32 = h3[(b * 3 + 2) * 196 + n];
      }
      unsigned short* orow = dst + (size_t)m * 768;
#pragma unroll
      for (int ni = 0; ni < 4; ++ni) {
        const int dcol = nb + ni * 16 + quad * 4;
        ushort4_t st;
        if (sel == 2) {
          const float4_t pwf0 = *(const float4_t*)(pw + dcol * 3);
          const float4_t pwf1 = *(const float4_t*)(pw + dcol * 3 + 4);
          const float4_t pwf2 = *(const float4_t*)(pw + dcol * 3 + 8);
          const float4_t pbf = *(const float4_t*)(pwb + dcol);
          float pwflat[12] = {pwf0[0], pwf0[1], pwf0[2], pwf0[3], pwf1[0], pwf1[1],
                              pwf1[2], pwf1[3], pwf2[0], pwf2[1], pwf2[2], pwf2[3]};
#pragma unroll
          for (int r = 0; r < 4; ++r) {
            const float v = acc[mi][ni][r] * gv + h30 * pwflat[3 * r] +
                            h31 * pwflat[3 * r + 1] + h32 * pwflat[3 * r + 2] + pbf[r];
            st[r] = f2bf(v);
          }
        } else {
#pragma unroll
          for (int r = 0; r < 4; ++r) st[r] = f2bf(acc[mi][ni][r]);
        }
        *(ushort4_t*)(orow + dcol) = st;
      }
    }
  } else if (MODE == M_PROJ || MODE == M_FC2) {
#pragma unroll
    for (int mi = 0; mi < 4; ++mi) {
      const int m = m0 + wm + mi * 16 + l15;
      const int nseq = m % 196;
      const float* rr0 = res0 + (size_t)m * 768;
      const float* rr1 = (MODE == M_PROJ) ? res1 + (size_t)nseq * 768 : nullptr;
      float* oo = oF + (size_t)m * 768;
#pragma unroll
      for (int ni = 0; ni < 4; ++ni) {
        const int col = n0 + wn + ni * 16 + quad * 4;
        const float4_t bb = *(const float4_t*)(bias + col);
        const float4_t r0v = *(const float4_t*)(rr0 + col);
        float4_t v;
#pragma unroll
        for (int r = 0; r < 4; ++r) v[r] = acc[mi][ni][r] + bb[r] + r0v[r];
        if (MODE == M_PROJ) {
          const float4_t r1v = *(const float4_t*)(rr1 + col);
#pragma unroll
          for (int r = 0; r < 4; ++r) v[r] += r1v[r];
        }
        *(float4_t*)(oo + col) = v;
      }
    }
  } else {  // M_GELU
#pragma unroll
    for (int mi = 0; mi < 4; ++mi) {
      const int m = m0 + wm + mi * 16 + l15;
      unsigned short* oo = oB + (size_t)m * Nd;
#pragma unroll
      for (int ni = 0; ni < 4; ++ni) {
        const int col = n0 + wn + ni * 16 + quad * 4;
        const float4_t bb = *(const float4_t*)(bias + col);
        ushort4_t st;
#pragma unroll
        for (int r = 0; r < 4; ++r) {
          const float t2 = acc[mi][ni][r] + bb[r];
          st[r] = f2bf(0.5f * t2 * (1.f + erff(t2 * 0.70710678118654752f)));
        }
        *(ushort4_t*)(oo + col) = st;
      }
    }
  }
}

// ---------------------------------------------------------------- V transpose: (b,n,h*96+d) -> (b,h,d,n224)
__global__ __launch_bounds__(256) void vtrans_kernel(const unsigned short* __restrict__ vg,
                                                     unsigned short* __restrict__ vt) {
  __shared__ unsigned short lds[96 * 226];
  const int bh = blockIdx.x, b = bh >> 3, h = bh & 7;
  const int tid = threadIdx.x;
  const unsigned short* base = vg + (size_t)(b * 196) * 768 + h * 96;
  for (int idx = tid; idx < 196 * 12; idx += 256) {
    const int n = idx / 12, c = idx % 12;
    const ushort8_t rv = *(const ushort8_t*)(base + (size_t)n * 768 + c * 8);
#pragma unroll
    for (int j = 0; j < 8; ++j) lds[(c * 8 + j) * 226 + n] = rv[j];
  }
  __syncthreads();
  unsigned short* ob = vt + (size_t)bh * (96 * 224);
  for (int idx = tid; idx < 96 * 28; idx += 256) {
    const int d = idx / 28, c = idx % 28;
    const int nn = c * 8;
    ushort8_t o;
#pragma unroll
    for (int j = 0; j < 8; ++j) o[j] = (nn + j < 196) ? lds[d * 226 + nn + j] : (unsigned short)0;
    *(ushort8_t*)(ob + (size_t)d * 224 + nn) = o;
  }
}

// ---------------------------------------------------------------- fused attention: 1 wave = 1 (head, q-tile)
__global__ __launch_bounds__(256, 2) void attn_kernel(
    const unsigned short* __restrict__ qg, const unsigned short* __restrict__ vg,
    const unsigned short* __restrict__ kg, const unsigned short* __restrict__ vt,
    unsigned short* __restrict__ att) {
  __shared__ __align__(16) unsigned short p_s[4][16][232];
  const int tid = threadIdx.x, w = tid >> 6, lane = tid & 63;
  const int l15 = lane & 15, quad = lane >> 4;
  // XCD-banded task mapping: 1664 blocks, 6656 wave-tasks; tasks sharing a head stay on one XCD
  const int l = blockIdx.x;
  const int bt = (l & 7) * 208 + (l >> 3);
  const int t = bt * 4 + w;
  const int bh = t / 13, qt = t - bh * 13;
  const int b = bh >> 3, h = bh & 7;
  const unsigned short* qb = qg + (size_t)(b * 196) * 768 + h * 96;
  const unsigned short* vb = vg + (size_t)(b * 196) * 768 + h * 96;
  const unsigned short* kb = kg + (size_t)(b * 196) * 768 + h * 96;
  const unsigned short* vtb = vt + (size_t)bh * (96 * 224);
  for (int i = lane; i < 256; i += 64) p_s[w][i >> 4][208 + (i & 15)] = 0;

  const size_t qoff = (size_t)(qt * 16 + l15) * 768 + quad * 8;
  short8_t a0, a1, a2;
  {
    const ushort8_t q0 = *(const ushort8_t*)(qb + qoff);
    const ushort8_t q1 = *(const ushort8_t*)(qb + qoff + 32);
    const ushort8_t q2 = *(const ushort8_t*)(qb + qoff + 64);
    const ushort8_t v0 = *(const ushort8_t*)(vb + qoff);
    const ushort8_t v1 = *(const ushort8_t*)(vb + qoff + 32);
    const ushort8_t v2 = *(const ushort8_t*)(vb + qoff + 64);
#pragma unroll
    for (int j = 0; j < 8; ++j) {
      a0[j] = (short)f2bf(bf2f(q0[j]) + bf2f(v0[j]));
      a1[j] = (short)f2bf(bf2f(q1[j]) + bf2f(v1[j]));
      a2[j] = (short)f2bf(bf2f(q2[j]) + bf2f(v2[j]));
    }
  }
  float4_t S[13];
#pragma unroll
  for (int c = 0; c < 13; ++c) S[c] = (float4_t){0.f, 0.f, 0.f, 0.f};
#pragma unroll
  for (int c = 0; c < 13; ++c) {
    const unsigned short* kr = kb + (size_t)(c * 16 + l15) * 768 + quad * 8;
    S[c] = mfma16(a0, *(const short8_t*)(kr), S[c]);
    S[c] = mfma16(a1, *(const short8_t*)(kr + 32), S[c]);
    S[c] = mfma16(a2, *(const short8_t*)(kr + 64), S[c]);
  }
  float mx[4] = {-1e30f, -1e30f, -1e30f, -1e30f};
#pragma unroll
  for (int c = 0; c < 13; ++c) {
    const bool okc = (c * 16 + l15) < 196;
#pragma unroll
    for (int r = 0; r < 4; ++r) {
      const float v = S[c][r] * ATT_SCALE;
      S[c][r] = okc ? v : -1e30f;
      mx[r] = fmaxf(mx[r], S[c][r]);
    }
  }
#pragma unroll
  for (int o = 1; o <= 8; o <<= 1)
#pragma unroll
    for (int r = 0; r < 4; ++r) mx[r] = fmaxf(mx[r], __shfl_xor(mx[r], o));
  float sum[4] = {0.f, 0.f, 0.f, 0.f};
#pragma unroll
  for (int c = 0; c < 13; ++c)
#pragma unroll
    for (int r = 0; r < 4; ++r) {
      const float e = __expf(S[c][r] - mx[r]);
      S[c][r] = e;
      sum[r] += e;
    }
#pragma unroll
  for (int o = 1; o <= 8; o <<= 1)
#pragma unroll
    for (int r = 0; r < 4; ++r) sum[r] += __shfl_xor(sum[r], o);
  float inv[4];
#pragma unroll
  for (int r = 0; r < 4; ++r) inv[r] = 1.f / sum[r];
#pragma unroll
  for (int c = 0; c < 13; ++c)
#pragma unroll
    for (int r = 0; r < 4; ++r)
      p_s[w][quad * 4 + r][c * 16 + l15] = f2bf(S[c][r] * inv[r]);

  // O^T form: O[ni][r] -> d = ni*16+quad*4+r, q-row = l15
  float4_t O[6];
#pragma unroll
  for (int ni = 0; ni < 6; ++ni) O[ni] = (float4_t){0.f, 0.f, 0.f, 0.f};
#pragma unroll
  for (int s = 0; s < 7; ++s) {
    short8_t pa = *(const short8_t*)(&p_s[w][l15][s * 32 + quad * 8]);
#pragma unroll
    for (int ni = 0; ni < 6; ++ni) {
      short8_t vf = *(const short8_t*)(vtb + (size_t)(ni * 16 + l15) * 224 + s * 32 + quad * 8);
      O[ni] = mfma16(vf, pa, O[ni]);
    }
  }
  // stage O into per-wave LDS (overwrites P; wave-lockstep makes this safe), then
  // write row-contiguous 192B segments
#pragma unroll
  for (int ni = 0; ni < 6; ++ni) {
    ushort4_t st = {f2bf(O[ni][0]), f2bf(O[ni][1]), f2bf(O[ni][2]), f2bf(O[ni][3])};
    *(ushort4_t*)(&p_s[w][l15][ni * 16 + quad * 4]) = st;
  }
  __asm__ volatile("s_waitcnt lgkmcnt(0)");
  unsigned short* ab = att + (size_t)(b * 196) * 768 + h * 96;
#pragma unroll
  for (int p = 0; p < 3; ++p) {
    const int idx = p * 64 + lane;
    const int row = idx / 12, c16 = idx - row * 12;
    const int m = qt * 16 + row;
    if (m < 196) {
      const ushort8_t o = *(const ushort8_t*)(&p_s[w][row][c16 * 8]);
      *(ushort8_t*)(ab + (size_t)m * 768 + c16 * 8) = o;
    }
  }
}

// ---------------------------------------------------------------- launch
extern "C" void kernel_launch(void* const* d_in, const int* in_sizes, int n_in,
                              void* d_out, int out_size, void* d_ws, size_t ws_size,
                              hipStream_t stream) {
  (void)in_sizes; (void)n_in; (void)out_size; (void)ws_size;
  const float* x      = (const float*)d_in[0];
  const float* xE     = (const float*)d_in[1];
  const float* pos    = (const float*)d_in[2];
  const float* dw_w   = (const float*)d_in[3];
  const float* dw_b   = (const float*)d_in[4];
  const float* pw_w   = (const float*)d_in[5];
  const float* pw_b   = (const float*)d_in[6];
  const float* qkv_w  = (const float*)d_in[7];
  const float* proj_w = (const float*)d_in[8];
  const float* proj_b = (const float*)d_in[9];
  const float* ln1_s  = (const float*)d_in[10];
  const float* ln1_b  = (const float*)d_in[11];
  const float* ln2_s  = (const float*)d_in[12];
  const float* ln2_b  = (const float*)d_in[13];
  const float* fc1_w  = (const float*)d_in[14];
  const float* fc1_b  = (const float*)d_in[15];
  const float* fc2_w  = (const float*)d_in[16];
  const float* fc2_b  = (const float*)d_in[17];
  float* out = (float*)d_out;

  char* ws = (char*)d_ws;
  size_t off = 0;
  auto alloc = [&](size_t bytes) -> void* {
    void* p = ws + off;
    off += (bytes + 255) & ~(size_t)255;
    return p;
  };
  unsigned short* wqkv  = (unsigned short*)alloc(1769472ull * 2);
  unsigned short* wproj = (unsigned short*)alloc(589824ull * 2);
  unsigned short* wfc1  = (unsigned short*)alloc(2359296ull * 2);
  unsigned short* wfc2  = (unsigned short*)alloc(2359296ull * 2);
  float* h3   = (float*)alloc(37632ull * 4);
  unsigned short* xln = (unsigned short*)alloc(9633792ull * 2);  // reused: att, h2
  float* maxn = (float*)alloc(12544ull * 4);
  float* aven = (float*)alloc(12544ull * 4);
  float* aveg = (float*)alloc(64ull * 4);
  float* s1   = (float*)alloc(12544ull * 4);
  float* gate = (float*)alloc(12544ull * 4);
  // big region: q,k,v ((12544+16) rows x 768) + vt (512*96*224); reused by gbuf (12544*3072)
  const size_t ROWP = 9646080ull;  // (12544+16)*768
  unsigned short* big = (unsigned short*)alloc((3ull * ROWP + 11010048ull) * 2);
  unsigned short* qg = big;
  unsigned short* kg = big + ROWP;
  unsigned short* vg = big + 2ull * ROWP;
  unsigned short* vt = big + 3ull * ROWP;
  unsigned short* att  = xln;
  unsigned short* h2   = xln;
  unsigned short* gbuf = big;  // 12544*3072 = 38.5M u16 < 39.9M region
  float* x2 = out;             // d_out doubles as x2

  cvt_kernel<<<dim3(6912), 256, 0, stream>>>(qkv_w, proj_w, fc1_w, fc2_w, wqkv, wproj, wfc1, wfc2);
  dwconv_kernel<<<dim3(192), 256, 0, stream>>>(xE, dw_w, dw_b, h3);
  ln1_kernel<<<dim3(12544), 256, 0, stream>>>(x, pos, ln1_s, ln1_b, xln, maxn, aven);
  gate1_kernel<<<dim3(64), 256, 0, stream>>>(maxn, aven, aveg, s1);
  gate2_kernel<<<dim3(196), 64, 0, stream>>>(aveg, aven, s1, gate);
  // QKV: tiles 98x18=1764 -> 8*221=1768 blocks
  gemm_bt<M_QKV><<<dim3(1768), 256, 0, stream>>>(xln, wqkv, 768, 2304, 18, 1764,
      nullptr, nullptr, nullptr, gate, h3, pw_w, pw_b, qg, kg, vg, nullptr, nullptr);
  vtrans_kernel<<<dim3(512), 256, 0, stream>>>(vg, vt);
  attn_kernel<<<dim3(1664), 256, 0, stream>>>(qg, vg, kg, vt, att);
  // PROJ: tiles 98x6=588 -> 8*74=592 blocks
  gemm_bt<M_PROJ><<<dim3(592), 256, 0, stream>>>(att, wproj, 768, 768, 6, 588,
      proj_b, x, pos, nullptr, nullptr, nullptr, nullptr, nullptr, nullptr, nullptr, x2, nullptr);
  ln2_kernel<<<dim3(12544), 256, 0, stream>>>(x2, ln2_s, ln2_b, h2);
  // GELU: tiles 98x24=2352 -> exactly 2352 blocks
  gemm_bt<M_GELU><<<dim3(2352), 256, 0, stream>>>(h2, wfc1, 768, 3072, 24, 2352,
      fc1_b, nullptr, nullptr, nullptr, nullptr, nullptr, nullptr, nullptr, nullptr, nullptr,
      nullptr, gbuf);
  // FC2: tiles 98x6=588 -> 592 blocks
  gemm_bt<M_FC2><<<dim3(592), 256, 0, stream>>>(gbuf, wfc2, 3072, 768, 6, 588,
      fc2_b, x2, nullptr, nullptr, nullptr, nullptr, nullptr, nullptr, nullptr, nullptr, out,
      nullptr);
}